// Round 1
// baseline (3261.990 us; speedup 1.0000x reference)
//
#include <hip/hip_runtime.h>
#include <stdint.h>

// Problem constants (fixed by reference: B=2, C=14, 96^3 voxels, epoch 0 -> ratio 0.1)
#define B_ 2
#define C_ 14
#define N_ 884736            // 96*96*96
#define K_ 88473             // int(N * 0.1)
#define NP 28                // B_*C_
#define M_ 13824             // N_/64 samples per pair for bracketing
#define RS_HI 1071           // sample rank for upper bracket (k/64 ~ 1382.4, -312 ~ 9 sigma)
#define RS_LO 1695           // +312
#define CAPMAX 131072        // candidate capacity per pair
#define EPS_ 1e-5

struct Ctrl {
  double sum_p2[NP];     // sum p^2 over selected (above-KHI part from K2, cand part from K3)
  double sum_p2t[NP];    // sum p^2 * t over selected
  double sum_t[NP];      // sum t over selected
  double sum_tall[NP];   // sum t over ALL N (validity mask)
  double cntA[NP];       // count of elements with err > KHI (exact, integer-valued)
  unsigned cand_cnt[NP];
  unsigned brackets[NP * 2];  // [2p]=KHI err bits, [2p+1]=KLO err bits
};

// ---------------------------------------------------------------------------
// K1: per-pair sampled bracket selection + accumulator zeroing
// ---------------------------------------------------------------------------
__device__ unsigned block_select_lds(const unsigned* samp, int n, int R,
                                     unsigned* hist, int tid) {
  // Select the R-th largest (1-indexed) 31-bit key from LDS array samp[0..n).
  __shared__ unsigned sb[4];
  // level 1: bits [30:20] (11 bits)
  for (int i = tid; i < 2048; i += 256) hist[i] = 0;
  __syncthreads();
  for (int i = tid; i < n; i += 256) atomicAdd(&hist[samp[i] >> 20], 1u);
  __syncthreads();
  if (tid == 0) {
    int rem = R; unsigned bsel = 0;
    for (int bb = 2047; bb >= 0; --bb) {
      unsigned h = hist[bb];
      if ((int)h >= rem) { bsel = (unsigned)bb; break; }
      rem -= (int)h;
    }
    sb[0] = bsel; sb[3] = (unsigned)rem;
  }
  __syncthreads();
  unsigned b1 = sb[0]; int rem1 = (int)sb[3];
  // level 2: bits [19:9]
  for (int i = tid; i < 2048; i += 256) hist[i] = 0;
  __syncthreads();
  for (int i = tid; i < n; i += 256) {
    unsigned kk = samp[i];
    if ((kk >> 20) == b1) atomicAdd(&hist[(kk >> 9) & 0x7FF], 1u);
  }
  __syncthreads();
  if (tid == 0) {
    int rem = rem1; unsigned bsel = 0;
    for (int bb = 2047; bb >= 0; --bb) {
      unsigned h = hist[bb];
      if ((int)h >= rem) { bsel = (unsigned)bb; break; }
      rem -= (int)h;
    }
    sb[1] = bsel; sb[3] = (unsigned)rem;
  }
  __syncthreads();
  unsigned b2 = sb[1]; int rem2 = (int)sb[3];
  // level 3: bits [8:0] (512 bins)
  for (int i = tid; i < 2048; i += 256) hist[i] = 0;
  __syncthreads();
  unsigned pfx = (b1 << 11) | b2;
  for (int i = tid; i < n; i += 256) {
    unsigned kk = samp[i];
    if ((kk >> 9) == pfx) atomicAdd(&hist[kk & 0x1FF], 1u);
  }
  __syncthreads();
  if (tid == 0) {
    int rem = rem2; unsigned bsel = 0;
    for (int bb = 511; bb >= 0; --bb) {
      unsigned h = hist[bb];
      if ((int)h >= rem) { bsel = (unsigned)bb; break; }
      rem -= (int)h;
    }
    sb[2] = bsel;
  }
  __syncthreads();
  unsigned res = (pfx << 9) | sb[2];
  __syncthreads();
  return res;
}

__global__ __launch_bounds__(256) void k1_bracket(const float* __restrict__ pred,
                                                  const float* __restrict__ targ,
                                                  Ctrl* __restrict__ ctrl) {
  __shared__ unsigned samp[M_];
  __shared__ unsigned hist[2048];
  int pair = blockIdx.x;
  int b = pair / C_, c = pair % C_;
  int tid = threadIdx.x;

  for (int i = tid; i < M_; i += 256) {
    float x[C_];
    float mx = -1e30f;
#pragma unroll
    for (int cc = 0; cc < C_; ++cc) {
      x[cc] = pred[(size_t)(b * C_ + cc) * N_ + i];
      mx = fmaxf(mx, x[cc]);
    }
    float s = 0.f;
#pragma unroll
    for (int cc = 0; cc < C_; ++cc) { x[cc] = __expf(x[cc] - mx); s += x[cc]; }
    float p = x[c] * (1.0f / s);
    float t = targ[(size_t)(b * C_ + c) * N_ + i];
    float err = fabsf(p - t);
    samp[i] = __float_as_uint(err);  // err >= 0 -> 31-bit monotone key
  }
  __syncthreads();

  unsigned khi = block_select_lds(samp, M_, RS_HI, hist, tid);
  unsigned klo = block_select_lds(samp, M_, RS_LO, hist, tid);

  if (tid == 0) {
    ctrl->brackets[2 * pair]     = khi;
    ctrl->brackets[2 * pair + 1] = klo;
    ctrl->sum_p2[pair] = 0.0;  ctrl->sum_p2t[pair] = 0.0;
    ctrl->sum_t[pair]  = 0.0;  ctrl->sum_tall[pair] = 0.0;
    ctrl->cntA[pair]   = 0.0;  ctrl->cand_cnt[pair] = 0u;
  }
}

// ---------------------------------------------------------------------------
// K2: main pass. 576 blocks/batch * 256 thr * 6 voxels = N exactly (no tail).
// ---------------------------------------------------------------------------
__global__ __launch_bounds__(256) void k2_main(const float* __restrict__ pred,
                                               const float* __restrict__ targ,
                                               Ctrl* __restrict__ ctrl,
                                               unsigned* __restrict__ cand_key,
                                               unsigned* __restrict__ cand_idx,
                                               unsigned cap) {
  int b = blockIdx.y;
  int tid = threadIdx.x;
  int lane = tid & 63;
  int wv = tid >> 6;
  __shared__ float s_part[4][C_ * 5];

  unsigned khi[C_], klo[C_];
#pragma unroll
  for (int c = 0; c < C_; ++c) {
    khi[c] = ctrl->brackets[2 * (b * C_ + c)];
    klo[c] = ctrl->brackets[2 * (b * C_ + c) + 1];
  }
  float a_p2[C_], a_p2t[C_], a_t[C_], a_cnt[C_], a_tall[C_];
#pragma unroll
  for (int c = 0; c < C_; ++c) {
    a_p2[c] = 0.f; a_p2t[c] = 0.f; a_t[c] = 0.f; a_cnt[c] = 0.f; a_tall[c] = 0.f;
  }
  const size_t base = (size_t)b * C_ * N_;
  const int stride = gridDim.x * 256;

  for (int n = blockIdx.x * 256 + tid; n < N_; n += stride) {
    float x[C_];
    float mx = -1e30f;
#pragma unroll
    for (int c = 0; c < C_; ++c) {
      x[c] = pred[base + (size_t)c * N_ + n];
      mx = fmaxf(mx, x[c]);
    }
    float s = 0.f;
#pragma unroll
    for (int c = 0; c < C_; ++c) { x[c] = __expf(x[c] - mx); s += x[c]; }
    float rs = 1.0f / s;
#pragma unroll
    for (int c = 0; c < C_; ++c) {
      float p = x[c] * rs;
      float t = targ[base + (size_t)c * N_ + n];
      float err = fabsf(p - t);
      unsigned eb = __float_as_uint(err);
      bool above  = eb > khi[c];
      bool iscand = (!above) && (eb > klo[c]);
      float m = above ? 1.f : 0.f;
      float pp = p * p;
      a_p2[c]  += m * pp;
      a_p2t[c] += m * pp * t;
      a_t[c]   += m * t;
      a_cnt[c] += m;
      a_tall[c] += t;
      unsigned long long mask = __ballot(iscand ? 1 : 0);
      if (mask) {
        int leader = __ffsll((long long)mask) - 1;
        unsigned base_off = 0;
        if (lane == leader)
          base_off = atomicAdd(&ctrl->cand_cnt[b * C_ + c], (unsigned)__popcll(mask));
        base_off = (unsigned)__shfl((int)base_off, leader);
        if (iscand) {
          unsigned off = base_off + (unsigned)__popcll(mask & ((1ull << lane) - 1ull));
          if (off < cap) {
            size_t cb = (size_t)(b * C_ + c) * cap + off;
            cand_key[cb] = (eb << 1) | (t > 0.5f ? 1u : 0u);
            cand_idx[cb] = (unsigned)n;
          }
        }
      }
    }
  }

  // block reduction: wave shuffle -> LDS -> double atomics (70 per block)
#pragma unroll
  for (int c = 0; c < C_; ++c) {
    float v0 = a_p2[c], v1 = a_p2t[c], v2 = a_t[c], v3 = a_cnt[c], v4 = a_tall[c];
    for (int o = 32; o > 0; o >>= 1) {
      v0 += __shfl_down(v0, o); v1 += __shfl_down(v1, o); v2 += __shfl_down(v2, o);
      v3 += __shfl_down(v3, o); v4 += __shfl_down(v4, o);
    }
    if (lane == 0) {
      s_part[wv][c * 5 + 0] = v0; s_part[wv][c * 5 + 1] = v1;
      s_part[wv][c * 5 + 2] = v2; s_part[wv][c * 5 + 3] = v3;
      s_part[wv][c * 5 + 4] = v4;
    }
  }
  __syncthreads();
  if (tid < C_ * 5) {
    double v = (double)s_part[0][tid] + (double)s_part[1][tid] +
               (double)s_part[2][tid] + (double)s_part[3][tid];
    int c = tid / 5, q = tid - c * 5;
    int pr = b * C_ + c;
    if      (q == 0) atomicAdd(&ctrl->sum_p2[pr],  v);
    else if (q == 1) atomicAdd(&ctrl->sum_p2t[pr], v);
    else if (q == 2) atomicAdd(&ctrl->sum_t[pr],   v);
    else if (q == 3) atomicAdd(&ctrl->cntA[pr],    v);
    else             atomicAdd(&ctrl->sum_tall[pr], v);
  }
}

// ---------------------------------------------------------------------------
// K3: per-pair exact selection among candidates (radix 11+11+9 on err bits),
// index-ordered tie resolution at the exact threshold (matches jax top_k).
// ---------------------------------------------------------------------------
#define TIECAP 512

__global__ __launch_bounds__(256) void k3_finish(Ctrl* __restrict__ ctrl,
                                                 const unsigned* __restrict__ cand_key,
                                                 const unsigned* __restrict__ cand_idx,
                                                 unsigned cap) {
  __shared__ unsigned hist[2048];
  __shared__ unsigned sb[4];
  __shared__ unsigned s_ties[TIECAP];
  __shared__ unsigned s_tiecnt;
  __shared__ float red[4][3];
  int pair = blockIdx.x;
  int tid = threadIdx.x;
  int lane = tid & 63, wv = tid >> 6;

  unsigned nc = ctrl->cand_cnt[pair];
  if (nc > cap) nc = cap;
  int r = K_ - (int)(ctrl->cntA[pair] + 0.5);
  if (r <= 0) return;                 // bracket failure fallback (should not happen)
  if (r > (int)nc) r = (int)nc;       // bracket failure fallback
  if (r <= 0) return;

  const unsigned* key = cand_key + (size_t)pair * cap;
  const unsigned* idx = cand_idx + (size_t)pair * cap;

  // ---- level 1: err bits [30:20] == key>>21
  for (int i = tid; i < 2048; i += 256) hist[i] = 0;
  __syncthreads();
  for (int i = tid; i < (int)nc; i += 256) atomicAdd(&hist[key[i] >> 21], 1u);
  __syncthreads();
  if (tid == 0) {
    int rem = r; unsigned bsel = 0;
    for (int bb = 2047; bb >= 0; --bb) {
      unsigned h = hist[bb];
      if ((int)h >= rem) { bsel = (unsigned)bb; break; }
      rem -= (int)h;
    }
    sb[0] = bsel; sb[3] = (unsigned)rem;
  }
  __syncthreads();
  unsigned b1 = sb[0]; int rem1 = (int)sb[3];
  // ---- level 2: err bits [19:9] == (key>>10)&0x7FF
  for (int i = tid; i < 2048; i += 256) hist[i] = 0;
  __syncthreads();
  for (int i = tid; i < (int)nc; i += 256) {
    unsigned kk = key[i];
    if ((kk >> 21) == b1) atomicAdd(&hist[(kk >> 10) & 0x7FF], 1u);
  }
  __syncthreads();
  if (tid == 0) {
    int rem = rem1; unsigned bsel = 0;
    for (int bb = 2047; bb >= 0; --bb) {
      unsigned h = hist[bb];
      if ((int)h >= rem) { bsel = (unsigned)bb; break; }
      rem -= (int)h;
    }
    sb[1] = bsel; sb[3] = (unsigned)rem;
  }
  __syncthreads();
  unsigned b2 = sb[1]; int rem2 = (int)sb[3];
  // ---- level 3: err bits [8:0] == (key>>1)&0x1FF
  for (int i = tid; i < 2048; i += 256) hist[i] = 0;
  __syncthreads();
  unsigned pfx22 = (b1 << 11) | b2;   // compare against key>>10 (err>>9)
  for (int i = tid; i < (int)nc; i += 256) {
    unsigned kk = key[i];
    if ((kk >> 10) == pfx22) atomicAdd(&hist[(kk >> 1) & 0x1FF], 1u);
  }
  __syncthreads();
  if (tid == 0) {
    int rem = rem2; unsigned bsel = 0;
    for (int bb = 511; bb >= 0; --bb) {
      unsigned h = hist[bb];
      if ((int)h >= rem) { bsel = (unsigned)bb; break; }
      rem -= (int)h;
    }
    sb[2] = bsel; sb[3] = (unsigned)rem;
    s_tiecnt = 0;
  }
  __syncthreads();
  unsigned tau = (pfx22 << 9) | sb[2];  // exact err bits of the r-th largest candidate
  int need = (int)sb[3];                // how many elements exactly == tau to take

  // ---- accumulate strictly-above + collect ties
  float f_p2 = 0.f, f_p2t = 0.f, f_t = 0.f;
  for (int i = tid; i < (int)nc; i += 256) {
    unsigned kk = key[i];
    unsigned eb = kk >> 1;
    if (eb > tau) {
      float err = __uint_as_float(eb);
      float t = (float)(kk & 1u);
      float p = (kk & 1u) ? (1.f - err) : err;
      float pp = p * p;
      f_p2 += pp; f_p2t += pp * t; f_t += t;
    } else if (eb == tau) {
      unsigned pos = atomicAdd(&s_tiecnt, 1u);
      if (pos < TIECAP) s_ties[pos] = (idx[i] << 1) | (kk & 1u);  // idx < 2^20
    }
  }
  for (int o = 32; o > 0; o >>= 1) {
    f_p2 += __shfl_down(f_p2, o); f_p2t += __shfl_down(f_p2t, o); f_t += __shfl_down(f_t, o);
  }
  if (lane == 0) { red[wv][0] = f_p2; red[wv][1] = f_p2t; red[wv][2] = f_t; }
  __syncthreads();

  if (tid == 0) {
    double d_p2  = (double)red[0][0] + red[1][0] + red[2][0] + red[3][0];
    double d_p2t = (double)red[0][1] + red[1][1] + red[2][1] + red[3][1];
    double d_t   = (double)red[0][2] + red[1][2] + red[2][2] + red[3][2];
    // ties at exactly tau: jax picks lowest indices first
    unsigned tc = s_tiecnt; if (tc > TIECAP) tc = TIECAP;
    int take = need; if (take > (int)tc) take = (int)tc;
    float errf = __uint_as_float(tau);
    for (int s = 0; s < take; ++s) {
      unsigned best = 0xFFFFFFFFu; int bi = -1;
      for (int j = 0; j < (int)tc; ++j)
        if (s_ties[j] < best) { best = s_ties[j]; bi = j; }
      if (bi < 0) break;
      s_ties[bi] = 0xFFFFFFFFu;
      float t = (float)(best & 1u);
      float p = (best & 1u) ? (1.f - errf) : errf;
      d_p2 += (double)(p * p); d_p2t += (double)(p * p) * t; d_t += (double)t;
    }
    ctrl->sum_p2[pair]  += d_p2;
    ctrl->sum_p2t[pair] += d_p2t;
    ctrl->sum_t[pair]   += d_t;
  }
}

// ---------------------------------------------------------------------------
// K4: final scalar
// ---------------------------------------------------------------------------
__global__ void k4_final(const Ctrl* __restrict__ ctrl, float* __restrict__ out) {
  if (threadIdx.x == 0 && blockIdx.x == 0) {
    double total = 0.0, nb = 0.0;
    for (int b = 0; b < B_; ++b) {
      double sl = 0.0, nv = 0.0;
      for (int c = 0; c < C_; ++c) {
        int pr = b * C_ + c;
        if (ctrl->sum_tall[pr] > 0.0) {
          double inter = ctrl->sum_p2t[pr];
          double uni = ctrl->sum_p2[pr] + ctrl->sum_t[pr];
          double dice = (2.0 * inter + EPS_) / (uni + EPS_);
          sl += 1.0 - dice;
          nv += 1.0;
        }
      }
      if (nv > 0.0) { total += sl / nv; nb += 1.0; }
    }
    out[0] = (float)(nb > 0.0 ? total / nb : 0.0);
  }
}

// ---------------------------------------------------------------------------
extern "C" void kernel_launch(void* const* d_in, const int* in_sizes, int n_in,
                              void* d_out, int out_size, void* d_ws, size_t ws_size,
                              hipStream_t stream) {
  const float* pred = (const float*)d_in[0];
  const float* targ = (const float*)d_in[1];
  Ctrl* ctrl = (Ctrl*)d_ws;
  unsigned cap = CAPMAX;
  if (ws_size > 4096) {
    size_t avail = (ws_size - 4096) / (8 * NP);  // 2 uints per candidate
    if (avail < (size_t)cap) cap = (unsigned)avail;
  }
  if (cap == 0) cap = 1;
  unsigned* cand_key = (unsigned*)((char*)d_ws + 4096);
  unsigned* cand_idx = cand_key + (size_t)NP * cap;
  float* out = (float*)d_out;

  k1_bracket<<<dim3(NP), dim3(256), 0, stream>>>(pred, targ, ctrl);
  k2_main<<<dim3(576, B_), dim3(256), 0, stream>>>(pred, targ, ctrl, cand_key, cand_idx, cap);
  k3_finish<<<dim3(NP), dim3(256), 0, stream>>>(ctrl, cand_key, cand_idx, cap);
  k4_final<<<dim3(1), dim3(1), 0, stream>>>(ctrl, out);
}

// Round 2
// 478.982 us; speedup vs baseline: 6.8103x; 6.8103x over previous
//
#include <hip/hip_runtime.h>
#include <stdint.h>

// Problem constants (fixed by reference: B=2, C=14, 96^3 voxels, epoch 0 -> ratio 0.1)
#define B_ 2
#define C_ 14
#define N_ 884736            // 96*96*96
#define K_ 88473             // int(N * 0.1)
#define NP 28                // B_*C_
#define M_ 13824             // N_/64 samples per pair for bracketing
#define RS_HI 1071           // sample rank for upper bracket (k/64 ~ 1382.4, -312 ~ 9 sigma)
#define RS_LO 1695           // +312
#define CAPMAX 131072        // candidate capacity per pair
#define EPS_ 1e-5
#define G2 576               // K2 blocks per batch (576*256*6 = N exactly)
#define CAPB 128             // per-block per-class LDS candidate staging (exp ~69, +7 sigma)
#define TIECAP 512
#define CCP 16               // cand_cnt padding: 16 uints = 64B -> one cache line per pair
#define PART_STRIDE 70       // 14 classes * 5 sums per K2 block

struct Ctrl {
  double sum_p2[NP];         // final: written by K3
  double sum_p2t[NP];
  double sum_t[NP];
  double sum_tall[NP];
  double cntA[NP];
  unsigned cand_cnt[NP * CCP];  // padded to 64B per pair (atomic contention fix)
  unsigned brackets[NP * 2];    // [2p]=KHI err bits, [2p+1]=KLO err bits
};

// ---------------------------------------------------------------------------
// Parallel "find bin containing the R-th largest" over a histogram in LDS.
// All 256 threads participate. Result -> sb[0]=bin, sb[1]=remaining rank in bin.
// ---------------------------------------------------------------------------
template <int NB>
__device__ void rank_bin(const unsigned* hist, int R, unsigned* sb, int tid) {
  __shared__ unsigned wtot[4];
  const int per = NB / 256;
  const int base = tid * per;
  unsigned local = 0;
#pragma unroll
  for (int j = 0; j < per; ++j) local += hist[base + j];
  int lane = tid & 63, wv = tid >> 6;
  unsigned v = local;
  // inclusive suffix-sum within wave (descending thread index = descending bins)
#pragma unroll
  for (int o = 1; o < 64; o <<= 1) {
    unsigned w = __shfl_down(v, o);
    if (lane + o < 64) v += w;
  }
  if (lane == 0) wtot[wv] = v;
  __syncthreads();
  unsigned excl = v - local;                 // within-wave exclusive suffix
  for (int w2 = wv + 1; w2 < 4; ++w2) excl += wtot[w2];
  if ((int)excl < R && R <= (int)(excl + local)) {
    unsigned rem = (unsigned)R - excl;
    for (int j = per - 1; j >= 0; --j) {
      unsigned h = hist[base + j];
      if (h >= rem) { sb[0] = (unsigned)(base + j); sb[1] = rem; break; }
      rem -= h;
    }
  }
  __syncthreads();
}

// ---------------------------------------------------------------------------
// K1: per-pair sampled bracket selection (3-level radix on 31-bit err keys)
// ---------------------------------------------------------------------------
__device__ unsigned select31(const unsigned* samp, int n, int R,
                             unsigned* hist, unsigned* sb, int tid) {
  // level 1: bits [30:20]
  for (int i = tid; i < 2048; i += 256) hist[i] = 0;
  __syncthreads();
  for (int i = tid; i < n; i += 256) atomicAdd(&hist[samp[i] >> 20], 1u);
  __syncthreads();
  rank_bin<2048>(hist, R, sb, tid);
  unsigned b1 = sb[0]; int r1 = (int)sb[1];
  __syncthreads();
  // level 2: bits [19:9]
  for (int i = tid; i < 2048; i += 256) hist[i] = 0;
  __syncthreads();
  for (int i = tid; i < n; i += 256) {
    unsigned kk = samp[i];
    if ((kk >> 20) == b1) atomicAdd(&hist[(kk >> 9) & 0x7FF], 1u);
  }
  __syncthreads();
  rank_bin<2048>(hist, r1, sb, tid);
  unsigned b2 = sb[0]; int r2 = (int)sb[1];
  unsigned pfx = (b1 << 11) | b2;
  __syncthreads();
  // level 3: bits [8:0]
  for (int i = tid; i < 512; i += 256) hist[i] = 0;
  __syncthreads();
  for (int i = tid; i < n; i += 256) {
    unsigned kk = samp[i];
    if ((kk >> 9) == pfx) atomicAdd(&hist[kk & 0x1FF], 1u);
  }
  __syncthreads();
  rank_bin<512>(hist, r2, sb, tid);
  unsigned res = (pfx << 9) | sb[0];
  __syncthreads();
  return res;
}

__global__ __launch_bounds__(256) void k1_bracket(const float* __restrict__ pred,
                                                  const float* __restrict__ targ,
                                                  Ctrl* __restrict__ ctrl) {
  __shared__ unsigned samp[M_];
  __shared__ unsigned hist[2048];
  __shared__ unsigned sb[2];
  int pair = blockIdx.x;
  int b = pair / C_, c = pair % C_;
  int tid = threadIdx.x;

  for (int i = tid; i < M_; i += 256) {
    float x[C_];
    float mx = -1e30f;
#pragma unroll
    for (int cc = 0; cc < C_; ++cc) {
      x[cc] = pred[(size_t)(b * C_ + cc) * N_ + i];
      mx = fmaxf(mx, x[cc]);
    }
    float s = 0.f;
#pragma unroll
    for (int cc = 0; cc < C_; ++cc) { x[cc] = __expf(x[cc] - mx); s += x[cc]; }
    float p = x[c] * (1.0f / s);
    float t = targ[(size_t)(b * C_ + c) * N_ + i];
    float err = fabsf(p - t);
    samp[i] = __float_as_uint(err);  // err >= 0 -> monotone 31-bit key
  }
  __syncthreads();

  unsigned khi = select31(samp, M_, RS_HI, hist, sb, tid);
  unsigned klo = select31(samp, M_, RS_LO, hist, sb, tid);

  if (tid == 0) {
    ctrl->brackets[2 * pair]     = khi;
    ctrl->brackets[2 * pair + 1] = klo;
  }
  if (tid < CCP) ctrl->cand_cnt[pair * CCP + tid] = 0u;
}

// ---------------------------------------------------------------------------
// K2: main pass. grid (576, B). 256 thr * 6 voxels = 1536 voxels/block.
// Candidates staged in LDS, flushed once per block per class (padded atomics).
// Partial sums written to workspace (no global double atomics).
// ---------------------------------------------------------------------------
__global__ __launch_bounds__(256) void k2_main(const float* __restrict__ pred,
                                               const float* __restrict__ targ,
                                               Ctrl* __restrict__ ctrl,
                                               double* __restrict__ part,
                                               unsigned* __restrict__ cand_key,
                                               unsigned* __restrict__ cand_idx,
                                               unsigned cap) {
  int b = blockIdx.y;
  int tid = threadIdx.x;
  int lane = tid & 63;
  int wv = tid >> 6;
  __shared__ unsigned s_cnt[C_];
  __shared__ unsigned s_base[C_];
  __shared__ unsigned s_khi[C_], s_klo[C_];
  __shared__ unsigned s_key[C_][CAPB];
  __shared__ unsigned s_idx[C_][CAPB];
  __shared__ float s_part[4][PART_STRIDE];

  int pr0 = b * C_;
  if (tid < C_) {
    s_khi[tid] = ctrl->brackets[2 * (pr0 + tid)];
    s_klo[tid] = ctrl->brackets[2 * (pr0 + tid) + 1];
    s_cnt[tid] = 0u;
  }
  __syncthreads();

  float a_p2[C_], a_p2t[C_];
  unsigned a_pk[C_];  // packed: cnt<<20 | tsel<<10 | tall  (each <= 6/thread)
#pragma unroll
  for (int c = 0; c < C_; ++c) { a_p2[c] = 0.f; a_p2t[c] = 0.f; a_pk[c] = 0u; }

  const size_t gbase = (size_t)b * C_ * N_;
  const int blk0 = blockIdx.x * 1536;

#pragma unroll 1
  for (int it = 0; it < 3; ++it) {
    int n0 = blk0 + it * 512 + tid * 2;
    float2 xv[C_];
    float mx0 = -1e30f, mx1 = -1e30f;
#pragma unroll
    for (int c = 0; c < C_; ++c) {
      xv[c] = *reinterpret_cast<const float2*>(&pred[gbase + (size_t)c * N_ + n0]);
      mx0 = fmaxf(mx0, xv[c].x);
      mx1 = fmaxf(mx1, xv[c].y);
    }
    float s0 = 0.f, s1 = 0.f;
#pragma unroll
    for (int c = 0; c < C_; ++c) {
      float e0 = __expf(xv[c].x - mx0);
      float e1 = __expf(xv[c].y - mx1);
      xv[c].x = e0; xv[c].y = e1;
      s0 += e0; s1 += e1;
    }
    float r0 = 1.0f / s0, r1 = 1.0f / s1;
#pragma unroll
    for (int c = 0; c < C_; ++c) {
      float2 t2 = *reinterpret_cast<const float2*>(&targ[gbase + (size_t)c * N_ + n0]);
      unsigned khi = s_khi[c], klo = s_klo[c];
#pragma unroll
      for (int h = 0; h < 2; ++h) {
        float p = (h == 0) ? xv[c].x * r0 : xv[c].y * r1;
        float t = (h == 0) ? t2.x : t2.y;
        int n = n0 + h;
        float err = fabsf(p - t);
        unsigned eb = __float_as_uint(err);
        bool above = eb > khi;
        bool iscand = (eb > klo) && !above;
        unsigned tbit = (t > 0.5f) ? 1u : 0u;
        if (above) {
          float pp = p * p;
          a_p2[c] += pp;
          a_p2t[c] += tbit ? pp : 0.f;
        }
        a_pk[c] += (above ? (1u << 20) : 0u) + ((above && tbit) ? (1u << 10) : 0u) + tbit;
        if (iscand) {
          unsigned pos = atomicAdd(&s_cnt[c], 1u);
          unsigned key = (eb << 1) | tbit;
          if (pos < CAPB) {
            s_key[c][pos] = key;
            s_idx[c][pos] = (unsigned)n;
          } else {  // rare overflow: direct global (still correct)
            unsigned off = atomicAdd(&ctrl->cand_cnt[(pr0 + c) * CCP], 1u);
            if (off < cap) {
              size_t cb = (size_t)(pr0 + c) * cap + off;
              cand_key[cb] = key;
              cand_idx[cb] = (unsigned)n;
            }
          }
        }
      }
    }
  }

  // block reduction of the 5 per-class sums -> s_part
#pragma unroll
  for (int c = 0; c < C_; ++c) {
    float v0 = a_p2[c], v1 = a_p2t[c];
    float v2 = (float)((a_pk[c] >> 10) & 0x3FF);
    float v3 = (float)(a_pk[c] >> 20);
    float v4 = (float)(a_pk[c] & 0x3FF);
    for (int o = 32; o > 0; o >>= 1) {
      v0 += __shfl_down(v0, o); v1 += __shfl_down(v1, o); v2 += __shfl_down(v2, o);
      v3 += __shfl_down(v3, o); v4 += __shfl_down(v4, o);
    }
    if (lane == 0) {
      s_part[wv][c * 5 + 0] = v0; s_part[wv][c * 5 + 1] = v1;
      s_part[wv][c * 5 + 2] = v2; s_part[wv][c * 5 + 3] = v3;
      s_part[wv][c * 5 + 4] = v4;
    }
  }
  __syncthreads();

  // one padded atomic per class per block to reserve candidate slots
  if (tid < C_) {
    unsigned cnt = s_cnt[tid]; if (cnt > CAPB) cnt = CAPB;
    s_base[tid] = atomicAdd(&ctrl->cand_cnt[(pr0 + tid) * CCP], cnt);
  }
  // per-block partial sums (no atomics)
  if (tid < PART_STRIDE) {
    double v = (double)s_part[0][tid] + (double)s_part[1][tid] +
               (double)s_part[2][tid] + (double)s_part[3][tid];
    part[(size_t)(b * G2 + blockIdx.x) * PART_STRIDE + tid] = v;
  }
  __syncthreads();

  // coalesced flush of staged candidates
  for (int c = 0; c < C_; ++c) {
    unsigned cnt = s_cnt[c]; if (cnt > CAPB) cnt = CAPB;
    unsigned bas = s_base[c];
    for (unsigned i = tid; i < cnt; i += 256) {
      unsigned off = bas + i;
      if (off < cap) {
        size_t cb = (size_t)(pr0 + c) * cap + off;
        cand_key[cb] = s_key[c][i];
        cand_idx[cb] = s_idx[c][i];
      }
    }
  }
}

// ---------------------------------------------------------------------------
// K3: reduce partials + per-pair exact selection among candidates
// (radix 11+11+9 on err bits), index-ordered tie resolution (matches jax).
// ---------------------------------------------------------------------------
__global__ __launch_bounds__(256) void k3_finish(Ctrl* __restrict__ ctrl,
                                                 const double* __restrict__ part,
                                                 const unsigned* __restrict__ cand_key,
                                                 const unsigned* __restrict__ cand_idx,
                                                 unsigned cap) {
  __shared__ unsigned hist[2048];
  __shared__ unsigned sb[2];
  __shared__ double s_red5[4][5];
  __shared__ double s_sum[5];
  __shared__ unsigned s_ties[TIECAP];
  __shared__ unsigned s_tiecnt;
  __shared__ float redf[4][3];
  int pair = blockIdx.x;
  int b = pair / C_, c = pair % C_;
  int tid = threadIdx.x;
  int lane = tid & 63, wv = tid >> 6;

  // ---- 1. reduce K2 partial sums for this pair
  double acc0 = 0, acc1 = 0, acc2 = 0, acc3 = 0, acc4 = 0;
  for (int g = tid; g < G2; g += 256) {
    const double* pp = part + (size_t)(b * G2 + g) * PART_STRIDE + c * 5;
    acc0 += pp[0]; acc1 += pp[1]; acc2 += pp[2]; acc3 += pp[3]; acc4 += pp[4];
  }
  for (int o = 32; o > 0; o >>= 1) {
    acc0 += __shfl_down(acc0, o); acc1 += __shfl_down(acc1, o);
    acc2 += __shfl_down(acc2, o); acc3 += __shfl_down(acc3, o);
    acc4 += __shfl_down(acc4, o);
  }
  if (lane == 0) {
    s_red5[wv][0] = acc0; s_red5[wv][1] = acc1; s_red5[wv][2] = acc2;
    s_red5[wv][3] = acc3; s_red5[wv][4] = acc4;
  }
  __syncthreads();
  if (tid == 0) {
    for (int q = 0; q < 5; ++q)
      s_sum[q] = s_red5[0][q] + s_red5[1][q] + s_red5[2][q] + s_red5[3][q];
    s_tiecnt = 0;
  }
  __syncthreads();
  double d_p2 = s_sum[0], d_p2t = s_sum[1], d_t = s_sum[2];
  double d_cnt = s_sum[3], d_tall = s_sum[4];

  unsigned nc = ctrl->cand_cnt[pair * CCP];
  if (nc > cap) nc = cap;
  int r = K_ - (int)(d_cnt + 0.5);
  if (r > (int)nc) r = (int)nc;  // fallback (bracket failure); should not trigger

  double add_p2 = 0, add_p2t = 0, add_t = 0;
  if (r > 0) {
    const unsigned* key = cand_key + (size_t)pair * cap;
    const unsigned* idx = cand_idx + (size_t)pair * cap;

    // level 1: err bits [30:20] == key>>21
    for (int i = tid; i < 2048; i += 256) hist[i] = 0;
    __syncthreads();
    for (int i = tid; i < (int)nc; i += 256) atomicAdd(&hist[key[i] >> 21], 1u);
    __syncthreads();
    rank_bin<2048>(hist, r, sb, tid);
    unsigned b1 = sb[0]; int r1 = (int)sb[1];
    __syncthreads();
    // level 2: err bits [19:9] == (key>>10)&0x7FF
    for (int i = tid; i < 2048; i += 256) hist[i] = 0;
    __syncthreads();
    for (int i = tid; i < (int)nc; i += 256) {
      unsigned kk = key[i];
      if ((kk >> 21) == b1) atomicAdd(&hist[(kk >> 10) & 0x7FF], 1u);
    }
    __syncthreads();
    rank_bin<2048>(hist, r1, sb, tid);
    unsigned b2 = sb[0]; int r2 = (int)sb[1];
    unsigned pfx22 = (b1 << 11) | b2;
    __syncthreads();
    // level 3: err bits [8:0] == (key>>1)&0x1FF
    for (int i = tid; i < 512; i += 256) hist[i] = 0;
    __syncthreads();
    for (int i = tid; i < (int)nc; i += 256) {
      unsigned kk = key[i];
      if ((kk >> 10) == pfx22) atomicAdd(&hist[(kk >> 1) & 0x1FF], 1u);
    }
    __syncthreads();
    rank_bin<512>(hist, r2, sb, tid);
    unsigned tau = (pfx22 << 9) | sb[0];
    int need = (int)sb[1];

    // accumulate strictly-above + collect ties at tau
    float f_p2 = 0.f, f_p2t = 0.f, f_t = 0.f;
    for (int i = tid; i < (int)nc; i += 256) {
      unsigned kk = key[i];
      unsigned eb = kk >> 1;
      if (eb > tau) {
        float err = __uint_as_float(eb);
        float t = (float)(kk & 1u);
        float p = (kk & 1u) ? (1.f - err) : err;
        float pp = p * p;
        f_p2 += pp; f_p2t += pp * t; f_t += t;
      } else if (eb == tau) {
        unsigned pos = atomicAdd(&s_tiecnt, 1u);
        if (pos < TIECAP) s_ties[pos] = (idx[i] << 1) | (kk & 1u);  // idx < 2^20
      }
    }
    for (int o = 32; o > 0; o >>= 1) {
      f_p2 += __shfl_down(f_p2, o); f_p2t += __shfl_down(f_p2t, o);
      f_t += __shfl_down(f_t, o);
    }
    if (lane == 0) { redf[wv][0] = f_p2; redf[wv][1] = f_p2t; redf[wv][2] = f_t; }
    __syncthreads();

    if (tid == 0) {
      add_p2  = (double)redf[0][0] + redf[1][0] + redf[2][0] + redf[3][0];
      add_p2t = (double)redf[0][1] + redf[1][1] + redf[2][1] + redf[3][1];
      add_t   = (double)redf[0][2] + redf[1][2] + redf[2][2] + redf[3][2];
      // ties at exactly tau: jax takes lowest indices first
      unsigned tc = s_tiecnt; if (tc > TIECAP) tc = TIECAP;
      int take = need; if (take > (int)tc) take = (int)tc;
      float errf = __uint_as_float(tau);
      for (int s = 0; s < take; ++s) {
        unsigned best = 0xFFFFFFFFu; int bi = -1;
        for (int j = 0; j < (int)tc; ++j)
          if (s_ties[j] < best) { best = s_ties[j]; bi = j; }
        if (bi < 0) break;
        s_ties[bi] = 0xFFFFFFFFu;
        float t = (float)(best & 1u);
        float p = (best & 1u) ? (1.f - errf) : errf;
        add_p2 += (double)(p * p); add_p2t += (double)(p * p) * t; add_t += (double)t;
      }
    }
  }

  if (tid == 0) {
    ctrl->sum_p2[pair]  = d_p2 + add_p2;
    ctrl->sum_p2t[pair] = d_p2t + add_p2t;
    ctrl->sum_t[pair]   = d_t + add_t;
    ctrl->sum_tall[pair] = d_tall;
    ctrl->cntA[pair]    = d_cnt;
  }
}

// ---------------------------------------------------------------------------
// K4: final scalar
// ---------------------------------------------------------------------------
__global__ void k4_final(const Ctrl* __restrict__ ctrl, float* __restrict__ out) {
  if (threadIdx.x == 0 && blockIdx.x == 0) {
    double total = 0.0, nb = 0.0;
    for (int b = 0; b < B_; ++b) {
      double sl = 0.0, nv = 0.0;
      for (int c = 0; c < C_; ++c) {
        int pr = b * C_ + c;
        if (ctrl->sum_tall[pr] > 0.0) {
          double inter = ctrl->sum_p2t[pr];
          double uni = ctrl->sum_p2[pr] + ctrl->sum_t[pr];
          double dice = (2.0 * inter + EPS_) / (uni + EPS_);
          sl += 1.0 - dice;
          nv += 1.0;
        }
      }
      if (nv > 0.0) { total += sl / nv; nb += 1.0; }
    }
    out[0] = (float)(nb > 0.0 ? total / nb : 0.0);
  }
}

// ---------------------------------------------------------------------------
extern "C" void kernel_launch(void* const* d_in, const int* in_sizes, int n_in,
                              void* d_out, int out_size, void* d_ws, size_t ws_size,
                              hipStream_t stream) {
  const float* pred = (const float*)d_in[0];
  const float* targ = (const float*)d_in[1];
  Ctrl* ctrl = (Ctrl*)d_ws;
  double* part = (double*)((char*)d_ws + 4096);
  size_t cand_off = 4096 + (size_t)(B_ * G2) * PART_STRIDE * sizeof(double);
  cand_off = (cand_off + 255) & ~(size_t)255;

  unsigned cap = CAPMAX;
  if (ws_size > cand_off + 1024) {
    size_t avail = (ws_size - cand_off) / (8 * NP);  // 2 uints per candidate
    if (avail < (size_t)cap) cap = (unsigned)avail;
  } else {
    cap = 1;
  }
  unsigned* cand_key = (unsigned*)((char*)d_ws + cand_off);
  unsigned* cand_idx = cand_key + (size_t)NP * cap;
  float* out = (float*)d_out;

  k1_bracket<<<dim3(NP), dim3(256), 0, stream>>>(pred, targ, ctrl);
  k2_main<<<dim3(G2, B_), dim3(256), 0, stream>>>(pred, targ, ctrl, part, cand_key, cand_idx, cap);
  k3_finish<<<dim3(NP), dim3(256), 0, stream>>>(ctrl, part, cand_key, cand_idx, cap);
  k4_final<<<dim3(1), dim3(1), 0, stream>>>(ctrl, out);
}

// Round 6
// 319.020 us; speedup vs baseline: 10.2250x; 1.5014x over previous
//
#include <hip/hip_runtime.h>
#include <stdint.h>

// Problem constants (fixed by reference: B=2, C=14, 96^3 voxels, epoch 0 -> ratio 0.1)
#define B_ 2
#define C_ 14
#define N_ 884736            // 96*96*96
#define K_ 88473             // int(N * 0.1)
#define NP 28                // B_*C_
#define M_ 27648             // N_/32 samples per pair for bracketing
#define MBLK 108             // M_/256
#define RS_HI 2465           // k/32 (=2764.8) - 300 (~6.3 sigma of order-stat noise)
#define RS_LO 3065           // + 300
#define CAPMAX 131072        // global candidate capacity per pair
#define EPS_ 1e-5
#define G2 864               // K2 blocks per batch: 864*256*4 = N exactly
#define CAPB 64              // per-block per-class LDS candidate staging (exp ~22)
#define TIECAP 512
#define CCP 16               // cand_cnt padding: 64B -> one cache line per pair
#define PS 70                // 14 classes * 5 sums per K2 block
#define KLDS 28672           // K3 LDS key staging capacity (112 KB)

struct Ctrl {
  double sum_p2[NP];
  double sum_p2t[NP];
  double sum_t[NP];
  double sum_tall[NP];
  double cntA[NP];
  unsigned cand_cnt[NP * CCP];
  unsigned brackets[NP * 2];   // [2p]=KHI err bits, [2p+1]=KLO err bits
};

#define COMP(v, h) ((h) == 0 ? (v).x : (h) == 1 ? (v).y : (h) == 2 ? (v).z : (v).w)

// ---------------------------------------------------------------------------
// Parallel "find bin containing the R-th largest" over an LDS histogram.
// Result -> sb[0]=bin, sb[1]=remaining rank within bin.
// ---------------------------------------------------------------------------
template <int NB>
__device__ void rank_bin(const unsigned* hist, int R, unsigned* sb, int tid) {
  __shared__ unsigned wtot[4];
  const int per = NB / 256;
  const int base = tid * per;
  unsigned local = 0;
#pragma unroll
  for (int j = 0; j < per; ++j) local += hist[base + j];
  int lane = tid & 63, wv = tid >> 6;
  unsigned v = local;
#pragma unroll
  for (int o = 1; o < 64; o <<= 1) {   // within-wave inclusive suffix-sum
    unsigned w = __shfl_down(v, o);
    if (lane + o < 64) v += w;
  }
  if (lane == 0) wtot[wv] = v;
  __syncthreads();
  unsigned excl = v - local;
  for (int w2 = wv + 1; w2 < 4; ++w2) excl += wtot[w2];
  if ((int)excl < R && R <= (int)(excl + local)) {   // exactly one thread true
    unsigned rem = (unsigned)R - excl;
    for (int j = per - 1; j >= 0; --j) {
      unsigned h = hist[base + j];
      if (h >= rem) { sb[0] = (unsigned)(base + j); sb[1] = rem; break; }
      rem -= h;
    }
  }
  __syncthreads();
}

// 3-level (11+11+9 bit) radix select of R-th largest 31-bit key from LDS array
__device__ unsigned select31(const unsigned* samp, int n, int R,
                             unsigned* hist, unsigned* sb, int tid) {
  for (int i = tid; i < 2048; i += 256) hist[i] = 0;
  __syncthreads();
  for (int i = tid; i < n; i += 256) atomicAdd(&hist[samp[i] >> 20], 1u);
  __syncthreads();
  rank_bin<2048>(hist, R, sb, tid);
  unsigned b1 = sb[0]; int r1 = (int)sb[1];
  __syncthreads();
  for (int i = tid; i < 2048; i += 256) hist[i] = 0;
  __syncthreads();
  for (int i = tid; i < n; i += 256) {
    unsigned kk = samp[i];
    if ((kk >> 20) == b1) atomicAdd(&hist[(kk >> 9) & 0x7FF], 1u);
  }
  __syncthreads();
  rank_bin<2048>(hist, r1, sb, tid);
  unsigned b2 = sb[0]; int r2 = (int)sb[1];
  unsigned pfx = (b1 << 11) | b2;
  __syncthreads();
  for (int i = tid; i < 512; i += 256) hist[i] = 0;
  __syncthreads();
  for (int i = tid; i < n; i += 256) {
    unsigned kk = samp[i];
    if ((kk >> 9) == pfx) atomicAdd(&hist[kk & 0x1FF], 1u);
  }
  __syncthreads();
  rank_bin<512>(hist, r2, sb, tid);
  unsigned res = (pfx << 9) | sb[0];
  __syncthreads();
  return res;
}

// ---------------------------------------------------------------------------
// K1a: wide sampling — compute err keys for M_ positions, all 14 classes.
// grid (108, B). One position per thread; all loads issued up front.
// ---------------------------------------------------------------------------
__global__ __launch_bounds__(256) void k1a_sample(const float* __restrict__ pred,
                                                  const float* __restrict__ targ,
                                                  unsigned* __restrict__ sampkeys) {
  int b = blockIdx.y;
  int pos = blockIdx.x * 256 + threadIdx.x;
  float x[C_], tv[C_];
#pragma unroll
  for (int c = 0; c < C_; ++c) x[c] = pred[(size_t)(b * C_ + c) * N_ + pos];
#pragma unroll
  for (int c = 0; c < C_; ++c) tv[c] = targ[(size_t)(b * C_ + c) * N_ + pos];
  float mx = x[0];
#pragma unroll
  for (int c = 1; c < C_; ++c) mx = fmaxf(mx, x[c]);
  float s = 0.f;
#pragma unroll
  for (int c = 0; c < C_; ++c) { x[c] = __expf(x[c] - mx); s += x[c]; }
  float rs = 1.0f / s;
#pragma unroll
  for (int c = 0; c < C_; ++c) {
    float err = fabsf(x[c] * rs - tv[c]);
    sampkeys[(size_t)(b * C_ + c) * M_ + pos] = __float_as_uint(err);
  }
}

// ---------------------------------------------------------------------------
// K1b: per-pair bracket selection from staged sample keys (all-LDS radix).
// ---------------------------------------------------------------------------
__global__ __launch_bounds__(256) void k1b_bracket(const unsigned* __restrict__ sampkeys,
                                                   Ctrl* __restrict__ ctrl) {
  __shared__ unsigned samp[M_];     // 108 KB
  __shared__ unsigned hist[2048];
  __shared__ unsigned sb[2];
  int pair = blockIdx.x;
  int tid = threadIdx.x;
  for (int i = tid; i < M_; i += 256) samp[i] = sampkeys[(size_t)pair * M_ + i];
  __syncthreads();
  unsigned khi = select31(samp, M_, RS_HI, hist, sb, tid);
  unsigned klo = select31(samp, M_, RS_LO, hist, sb, tid);
  if (tid == 0) {
    ctrl->brackets[2 * pair] = khi;
    ctrl->brackets[2 * pair + 1] = klo;
  }
  if (tid < CCP) ctrl->cand_cnt[pair * CCP + tid] = 0u;
}

// ---------------------------------------------------------------------------
// K2: main pass. grid (864, B); 4 voxels/thread via float4; ALL 28 loads
// issued up front (MLP), single shot (no loop). Candidates staged in LDS.
// ---------------------------------------------------------------------------
__global__ __launch_bounds__(256) void k2_main(const float* __restrict__ pred,
                                               const float* __restrict__ targ,
                                               Ctrl* __restrict__ ctrl,
                                               double* __restrict__ part,
                                               unsigned* __restrict__ cand_key,
                                               unsigned* __restrict__ cand_idx,
                                               unsigned cap) {
  int b = blockIdx.y;
  int tid = threadIdx.x;
  int lane = tid & 63;
  int wv = tid >> 6;
  __shared__ unsigned s_cnt[C_], s_base[C_], s_khi[C_], s_klo[C_];
  __shared__ unsigned s_key[C_][CAPB];
  __shared__ unsigned s_idx[C_][CAPB];
  __shared__ float s_part[4][PS];

  int pr0 = b * C_;
  if (tid < C_) {
    s_khi[tid] = ctrl->brackets[2 * (pr0 + tid)];
    s_klo[tid] = ctrl->brackets[2 * (pr0 + tid) + 1];
    s_cnt[tid] = 0u;
  }
  __syncthreads();

  const size_t gbase = (size_t)b * C_ * N_;
  const int n0 = blockIdx.x * 1024 + tid * 4;

  float4 xp[C_], xt[C_];
#pragma unroll
  for (int c = 0; c < C_; ++c)
    xp[c] = *reinterpret_cast<const float4*>(pred + gbase + (size_t)c * N_ + n0);
#pragma unroll
  for (int c = 0; c < C_; ++c)
    xt[c] = *reinterpret_cast<const float4*>(targ + gbase + (size_t)c * N_ + n0);

  float4 mx = xp[0];
#pragma unroll
  for (int c = 1; c < C_; ++c) {
    mx.x = fmaxf(mx.x, xp[c].x); mx.y = fmaxf(mx.y, xp[c].y);
    mx.z = fmaxf(mx.z, xp[c].z); mx.w = fmaxf(mx.w, xp[c].w);
  }
  float4 sum; sum.x = 0.f; sum.y = 0.f; sum.z = 0.f; sum.w = 0.f;
#pragma unroll
  for (int c = 0; c < C_; ++c) {
    xp[c].x = __expf(xp[c].x - mx.x); sum.x += xp[c].x;
    xp[c].y = __expf(xp[c].y - mx.y); sum.y += xp[c].y;
    xp[c].z = __expf(xp[c].z - mx.z); sum.z += xp[c].z;
    xp[c].w = __expf(xp[c].w - mx.w); sum.w += xp[c].w;
  }
  float4 rs;
  rs.x = 1.0f / sum.x; rs.y = 1.0f / sum.y; rs.z = 1.0f / sum.z; rs.w = 1.0f / sum.w;

  float a_p2[C_], a_p2t[C_];
  unsigned a_pk[C_];   // packed per-thread counts: cnt<<20 | tsel<<10 | tall (each <=4)
#pragma unroll
  for (int c = 0; c < C_; ++c) { a_p2[c] = 0.f; a_p2t[c] = 0.f; a_pk[c] = 0u; }

#pragma unroll
  for (int c = 0; c < C_; ++c) {
    unsigned khi = s_khi[c], klo = s_klo[c];
#pragma unroll
    for (int h = 0; h < 4; ++h) {
      float p = COMP(xp[c], h) * COMP(rs, h);
      float t = COMP(xt[c], h);
      float err = fabsf(p - t);
      unsigned eb = __float_as_uint(err);
      bool above = eb > khi;
      bool iscand = (eb > klo) && !above;
      unsigned tbit = (t > 0.5f) ? 1u : 0u;
      if (above) {
        float pp = p * p;
        a_p2[c] += pp;
        if (tbit) a_p2t[c] += pp;
      }
      a_pk[c] += (above ? (1u << 20) : 0u) + ((above && tbit) ? (1u << 10) : 0u) + tbit;
      if (iscand) {
        unsigned pos = atomicAdd(&s_cnt[c], 1u);
        unsigned key = (eb << 1) | tbit;
        if (pos < CAPB) {
          s_key[c][pos] = key;
          s_idx[c][pos] = (unsigned)(n0 + h);
        } else {   // rare overflow: direct global (padded counter), still correct
          unsigned off = atomicAdd(&ctrl->cand_cnt[(pr0 + c) * CCP], 1u);
          if (off < cap) {
            size_t cb = (size_t)(pr0 + c) * cap + off;
            cand_key[cb] = key;
            cand_idx[cb] = (unsigned)(n0 + h);
          }
        }
      }
    }
  }

  // block reduction: 3 chains per class (p2, p2t, packed counts)
#pragma unroll
  for (int c = 0; c < C_; ++c) {
    float v0 = a_p2[c], v1 = a_p2t[c];
    unsigned u2 = a_pk[c];
    for (int o = 32; o > 0; o >>= 1) {
      v0 += __shfl_down(v0, o);
      v1 += __shfl_down(v1, o);
      u2 += (unsigned)__shfl_down((int)u2, o);   // wave-sum fields <=256, no carry
    }
    if (lane == 0) {
      s_part[wv][c * 5 + 0] = v0;
      s_part[wv][c * 5 + 1] = v1;
      s_part[wv][c * 5 + 2] = (float)((u2 >> 10) & 0x3FF);  // tsel
      s_part[wv][c * 5 + 3] = (float)(u2 >> 20);            // cntA
      s_part[wv][c * 5 + 4] = (float)(u2 & 0x3FF);          // tall
    }
  }
  __syncthreads();

  if (tid < C_) {   // one padded global atomic per class per block
    unsigned cnt = s_cnt[tid]; if (cnt > CAPB) cnt = CAPB;
    s_base[tid] = atomicAdd(&ctrl->cand_cnt[(pr0 + tid) * CCP], cnt);
  }
  if (tid < PS) {   // per-block partial sums, no atomics
    double v = (double)s_part[0][tid] + (double)s_part[1][tid] +
               (double)s_part[2][tid] + (double)s_part[3][tid];
    part[(size_t)(b * G2 + blockIdx.x) * PS + tid] = v;
  }
  __syncthreads();

  for (int c = 0; c < C_; ++c) {   // coalesced candidate flush
    unsigned cnt = s_cnt[c]; if (cnt > CAPB) cnt = CAPB;
    unsigned bas = s_base[c];
    for (unsigned i = tid; i < cnt; i += 256) {
      unsigned off = bas + i;
      if (off < cap) {
        size_t cb = (size_t)(pr0 + c) * cap + off;
        cand_key[cb] = s_key[c][i];
        cand_idx[cb] = s_idx[c][i];
      }
    }
  }
}

// ---------------------------------------------------------------------------
// K3: reduce partials + exact selection among candidates. Keys staged in LDS
// (112 KB) -> one global read + 3 LDS histogram passes + LDS accumulate.
// ---------------------------------------------------------------------------
__global__ __launch_bounds__(256) void k3_finish(Ctrl* __restrict__ ctrl,
                                                 const double* __restrict__ part,
                                                 const unsigned* __restrict__ cand_key,
                                                 const unsigned* __restrict__ cand_idx,
                                                 unsigned cap) {
  __shared__ unsigned s_keys[KLDS];    // 112 KB
  __shared__ unsigned hist[2048];
  __shared__ unsigned sb[2];
  __shared__ double s_red5[4][5];
  __shared__ double s_sum[5];
  __shared__ unsigned s_ties[TIECAP];
  __shared__ unsigned s_tiecnt;
  __shared__ float redf[4][3];
  int pair = blockIdx.x;
  int b = pair / C_, c = pair % C_;
  int tid = threadIdx.x;
  int lane = tid & 63, wv = tid >> 6;

  // 1. reduce K2 partial sums for this pair
  double acc0 = 0, acc1 = 0, acc2 = 0, acc3 = 0, acc4 = 0;
  for (int g = tid; g < G2; g += 256) {
    const double* pp = part + (size_t)(b * G2 + g) * PS + c * 5;
    acc0 += pp[0]; acc1 += pp[1]; acc2 += pp[2]; acc3 += pp[3]; acc4 += pp[4];
  }
  for (int o = 32; o > 0; o >>= 1) {
    acc0 += __shfl_down(acc0, o); acc1 += __shfl_down(acc1, o);
    acc2 += __shfl_down(acc2, o); acc3 += __shfl_down(acc3, o);
    acc4 += __shfl_down(acc4, o);
  }
  if (lane == 0) {
    s_red5[wv][0] = acc0; s_red5[wv][1] = acc1; s_red5[wv][2] = acc2;
    s_red5[wv][3] = acc3; s_red5[wv][4] = acc4;
  }
  __syncthreads();
  if (tid == 0) {
    for (int q = 0; q < 5; ++q)
      s_sum[q] = s_red5[0][q] + s_red5[1][q] + s_red5[2][q] + s_red5[3][q];
    s_tiecnt = 0;
  }
  __syncthreads();
  double d_p2 = s_sum[0], d_p2t = s_sum[1], d_t = s_sum[2];
  double d_cnt = s_sum[3], d_tall = s_sum[4];

  unsigned nc = ctrl->cand_cnt[pair * CCP];
  if (nc > cap) nc = cap;
  int r = K_ - (int)(d_cnt + 0.5);
  if (r > (int)nc) r = (int)nc;   // fallback (bracket failure); never expected

  double add_p2 = 0, add_p2t = 0, add_t = 0;
  if (r > 0) {
    const unsigned* gkey = cand_key + (size_t)pair * cap;
    const unsigned* gidx = cand_idx + (size_t)pair * cap;
    bool in_lds = (nc <= KLDS);
    if (in_lds)
      for (int i = tid; i < (int)nc; i += 256) s_keys[i] = gkey[i];
    __syncthreads();
    const unsigned* key = in_lds ? (const unsigned*)s_keys : gkey;

    // level 1: err bits [30:20] == key>>21
    for (int i = tid; i < 2048; i += 256) hist[i] = 0;
    __syncthreads();
    for (int i = tid; i < (int)nc; i += 256) atomicAdd(&hist[key[i] >> 21], 1u);
    __syncthreads();
    rank_bin<2048>(hist, r, sb, tid);
    unsigned b1 = sb[0]; int r1 = (int)sb[1];
    __syncthreads();
    // level 2: err bits [19:9]
    for (int i = tid; i < 2048; i += 256) hist[i] = 0;
    __syncthreads();
    for (int i = tid; i < (int)nc; i += 256) {
      unsigned kk = key[i];
      if ((kk >> 21) == b1) atomicAdd(&hist[(kk >> 10) & 0x7FF], 1u);
    }
    __syncthreads();
    rank_bin<2048>(hist, r1, sb, tid);
    unsigned b2 = sb[0]; int r2 = (int)sb[1];
    unsigned pfx22 = (b1 << 11) | b2;
    __syncthreads();
    // level 3: err bits [8:0]
    for (int i = tid; i < 512; i += 256) hist[i] = 0;
    __syncthreads();
    for (int i = tid; i < (int)nc; i += 256) {
      unsigned kk = key[i];
      if ((kk >> 10) == pfx22) atomicAdd(&hist[(kk >> 1) & 0x1FF], 1u);
    }
    __syncthreads();
    rank_bin<512>(hist, r2, sb, tid);
    unsigned tau = (pfx22 << 9) | sb[0];
    int need = (int)sb[1];

    // accumulate strictly-above + collect ties at tau
    float f_p2 = 0.f, f_p2t = 0.f, f_t = 0.f;
    for (int i = tid; i < (int)nc; i += 256) {
      unsigned kk = key[i];
      unsigned eb = kk >> 1;
      if (eb > tau) {
        float err = __uint_as_float(eb);
        float t = (float)(kk & 1u);
        float p = (kk & 1u) ? (1.f - err) : err;
        float pp = p * p;
        f_p2 += pp; f_p2t += pp * t; f_t += t;
      } else if (eb == tau) {
        unsigned pos = atomicAdd(&s_tiecnt, 1u);
        if (pos < TIECAP) s_ties[pos] = (gidx[i] << 1) | (kk & 1u);  // idx < 2^20
      }
    }
    for (int o = 32; o > 0; o >>= 1) {
      f_p2 += __shfl_down(f_p2, o); f_p2t += __shfl_down(f_p2t, o);
      f_t += __shfl_down(f_t, o);
    }
    if (lane == 0) { redf[wv][0] = f_p2; redf[wv][1] = f_p2t; redf[wv][2] = f_t; }
    __syncthreads();

    if (tid == 0) {
      add_p2  = (double)redf[0][0] + redf[1][0] + redf[2][0] + redf[3][0];
      add_p2t = (double)redf[0][1] + redf[1][1] + redf[2][1] + redf[3][1];
      add_t   = (double)redf[0][2] + redf[1][2] + redf[2][2] + redf[3][2];
      // ties at exactly tau: jax takes lowest indices first
      unsigned tc = s_tiecnt; if (tc > TIECAP) tc = TIECAP;
      int take = need; if (take > (int)tc) take = (int)tc;
      float errf = __uint_as_float(tau);
      for (int s = 0; s < take; ++s) {
        unsigned best = 0xFFFFFFFFu; int bi = -1;
        for (int j = 0; j < (int)tc; ++j)
          if (s_ties[j] < best) { best = s_ties[j]; bi = j; }
        if (bi < 0) break;
        s_ties[bi] = 0xFFFFFFFFu;
        float t = (float)(best & 1u);
        float p = (best & 1u) ? (1.f - errf) : errf;
        add_p2 += (double)(p * p); add_p2t += (double)(p * p) * t; add_t += (double)t;
      }
    }
  }

  if (tid == 0) {
    ctrl->sum_p2[pair]   = d_p2 + add_p2;
    ctrl->sum_p2t[pair]  = d_p2t + add_p2t;
    ctrl->sum_t[pair]    = d_t + add_t;
    ctrl->sum_tall[pair] = d_tall;
    ctrl->cntA[pair]     = d_cnt;
  }
}

// ---------------------------------------------------------------------------
// K4: final scalar
// ---------------------------------------------------------------------------
__global__ void k4_final(const Ctrl* __restrict__ ctrl, float* __restrict__ out) {
  if (threadIdx.x == 0 && blockIdx.x == 0) {
    double total = 0.0, nb = 0.0;
    for (int b = 0; b < B_; ++b) {
      double sl = 0.0, nv = 0.0;
      for (int c = 0; c < C_; ++c) {
        int pr = b * C_ + c;
        if (ctrl->sum_tall[pr] > 0.0) {
          double inter = ctrl->sum_p2t[pr];
          double uni = ctrl->sum_p2[pr] + ctrl->sum_t[pr];
          double dice = (2.0 * inter + EPS_) / (uni + EPS_);
          sl += 1.0 - dice;
          nv += 1.0;
        }
      }
      if (nv > 0.0) { total += sl / nv; nb += 1.0; }
    }
    out[0] = (float)(nb > 0.0 ? total / nb : 0.0);
  }
}

// ---------------------------------------------------------------------------
extern "C" void kernel_launch(void* const* d_in, const int* in_sizes, int n_in,
                              void* d_out, int out_size, void* d_ws, size_t ws_size,
                              hipStream_t stream) {
  const float* pred = (const float*)d_in[0];
  const float* targ = (const float*)d_in[1];
  Ctrl* ctrl = (Ctrl*)d_ws;
  double* part = (double*)((char*)d_ws + 4096);
  size_t part_bytes = (size_t)(B_ * G2) * PS * sizeof(double);   // 968 KB
  size_t samp_off = (4096 + part_bytes + 255) & ~(size_t)255;
  unsigned* sampkeys = (unsigned*)((char*)d_ws + samp_off);
  size_t cand_off = (samp_off + (size_t)NP * M_ * 4 + 255) & ~(size_t)255;

  unsigned cap = CAPMAX;
  if (ws_size > cand_off + 1024) {
    size_t avail = (ws_size - cand_off) / (8 * NP);   // 2 uints per candidate
    if (avail < (size_t)cap) cap = (unsigned)avail;
  } else {
    cap = 1;
  }
  unsigned* cand_key = (unsigned*)((char*)d_ws + cand_off);
  unsigned* cand_idx = cand_key + (size_t)NP * cap;
  float* out = (float*)d_out;

  k1a_sample<<<dim3(MBLK, B_), dim3(256), 0, stream>>>(pred, targ, sampkeys);
  k1b_bracket<<<dim3(NP), dim3(256), 0, stream>>>(sampkeys, ctrl);
  k2_main<<<dim3(G2, B_), dim3(256), 0, stream>>>(pred, targ, ctrl, part, cand_key, cand_idx, cap);
  k3_finish<<<dim3(NP), dim3(256), 0, stream>>>(ctrl, part, cand_key, cand_idx, cap);
  k4_final<<<dim3(1), dim3(1), 0, stream>>>(ctrl, out);
}

// Round 8
// 311.095 us; speedup vs baseline: 10.4855x; 1.0255x over previous
//
#include <hip/hip_runtime.h>
#include <stdint.h>

// Problem constants (fixed by reference: B=2, C=14, 96^3 voxels, epoch 0 -> ratio 0.1)
#define B_ 2
#define C_ 14
#define N_ 884736            // 96*96*96
#define K_ 88473             // int(N * 0.1)
#define NP 28                // B_*C_
#define M_ 27648             // N_/32 samples per pair for bracketing
#define MBLK 108             // M_/256
#define RS_HI 2465           // k/32 (=2764.8) - 300 (~6 sigma of order-stat noise)
#define RS_LO 3065           // + 300
#define CAPMAX 131072        // global candidate capacity per pair
#define EPS_ 1e-5
#define G2 864               // K2 blocks per batch: 864*256*4 = N exactly
#define CAPB 64              // per-block per-class LDS candidate staging (exp ~22)
#define TIECAP 512
#define CCP 16               // cand_cnt padding: 64B -> one cache line per pair
#define PS 70                // 14 classes * 5 sums per K2 block
#define KLDS 28672           // K3 LDS key staging capacity (112 KB)

struct Ctrl {
  double sum_p2[NP];
  double sum_p2t[NP];
  double sum_t[NP];
  double sum_tall[NP];
  double cntA[NP];
  unsigned cand_cnt[NP * CCP];
  unsigned brackets[NP * 2];   // [2p]=KHI err bits, [2p+1]=KLO err bits
};

#define COMP(v, h) ((h) == 0 ? (v).x : (h) == 1 ? (v).y : (h) == 2 ? (v).z : (v).w)

// ---------------------------------------------------------------------------
// Parallel "find bin containing the R-th largest" over an LDS histogram.
// Result -> sb[0]=bin, sb[1]=remaining rank within bin.
// ---------------------------------------------------------------------------
template <int NB>
__device__ void rank_bin(const unsigned* hist, int R, unsigned* sb, int tid) {
  __shared__ unsigned wtot[4];
  const int per = NB / 256;
  const int base = tid * per;
  unsigned local = 0;
#pragma unroll
  for (int j = 0; j < per; ++j) local += hist[base + j];
  int lane = tid & 63, wv = tid >> 6;
  unsigned v = local;
#pragma unroll
  for (int o = 1; o < 64; o <<= 1) {   // within-wave inclusive suffix-sum
    unsigned w = __shfl_down(v, o);
    if (lane + o < 64) v += w;
  }
  if (lane == 0) wtot[wv] = v;
  __syncthreads();
  unsigned excl = v - local;
  for (int w2 = wv + 1; w2 < 4; ++w2) excl += wtot[w2];
  if ((int)excl < R && R <= (int)(excl + local)) {   // exactly one thread true
    unsigned rem = (unsigned)R - excl;
    for (int j = per - 1; j >= 0; --j) {
      unsigned h = hist[base + j];
      if (h >= rem) { sb[0] = (unsigned)(base + j); sb[1] = rem; break; }
      rem -= h;
    }
  }
  __syncthreads();
}

// ---------------------------------------------------------------------------
// K1a: wide sampling — compute err keys for M_ positions, all 14 classes.
// ---------------------------------------------------------------------------
__global__ __launch_bounds__(256) void k1a_sample(const float* __restrict__ pred,
                                                  const float* __restrict__ targ,
                                                  unsigned* __restrict__ sampkeys) {
  int b = blockIdx.y;
  int pos = blockIdx.x * 256 + threadIdx.x;
  float x[C_], tv[C_];
#pragma unroll
  for (int c = 0; c < C_; ++c) x[c] = pred[(size_t)(b * C_ + c) * N_ + pos];
#pragma unroll
  for (int c = 0; c < C_; ++c) tv[c] = targ[(size_t)(b * C_ + c) * N_ + pos];
  float mx = x[0];
#pragma unroll
  for (int c = 1; c < C_; ++c) mx = fmaxf(mx, x[c]);
  float s = 0.f;
#pragma unroll
  for (int c = 0; c < C_; ++c) { x[c] = __expf(x[c] - mx); s += x[c]; }
  float rs = 1.0f / s;
#pragma unroll
  for (int c = 0; c < C_; ++c) {
    float err = fabsf(x[c] * rs - tv[c]);
    sampkeys[(size_t)(b * C_ + c) * M_ + pos] = __float_as_uint(err);
  }
}

// ---------------------------------------------------------------------------
// K1b: per-pair bracket selection. Fused KHI/KLO select: one scan per radix
// level fills dual histograms (3 scans total instead of 6).
// ---------------------------------------------------------------------------
__global__ __launch_bounds__(256) void k1b_bracket(const unsigned* __restrict__ sampkeys,
                                                   Ctrl* __restrict__ ctrl) {
  __shared__ unsigned samp[M_];     // 108 KB
  __shared__ unsigned histH[2048], histL[2048];
  __shared__ unsigned sb[2];
  int pair = blockIdx.x;
  int tid = threadIdx.x;
  for (int i = tid; i < M_; i += 256) samp[i] = sampkeys[(size_t)pair * M_ + i];
  for (int i = tid; i < 2048; i += 256) histH[i] = 0;
  __syncthreads();

  // pass 1: bits [30:20] — shared histogram for both ranks
  for (int i = tid; i < M_; i += 256) atomicAdd(&histH[samp[i] >> 20], 1u);
  __syncthreads();
  rank_bin<2048>(histH, RS_HI, sb, tid);
  unsigned b1h = sb[0]; int r1h = (int)sb[1];
  __syncthreads();
  rank_bin<2048>(histH, RS_LO, sb, tid);
  unsigned b1l = sb[0]; int r1l = (int)sb[1];
  __syncthreads();

  // pass 2: bits [19:9] — dual histograms, single scan
  for (int i = tid; i < 2048; i += 256) { histH[i] = 0; histL[i] = 0; }
  __syncthreads();
  for (int i = tid; i < M_; i += 256) {
    unsigned kk = samp[i];
    unsigned top = kk >> 20;
    if (top == b1h) atomicAdd(&histH[(kk >> 9) & 0x7FF], 1u);
    if (top == b1l) atomicAdd(&histL[(kk >> 9) & 0x7FF], 1u);
  }
  __syncthreads();
  rank_bin<2048>(histH, r1h, sb, tid);
  unsigned b2h = sb[0]; int r2h = (int)sb[1];
  __syncthreads();
  rank_bin<2048>(histL, r1l, sb, tid);
  unsigned b2l = sb[0]; int r2l = (int)sb[1];
  unsigned pfxh = (b1h << 11) | b2h;
  unsigned pfxl = (b1l << 11) | b2l;
  __syncthreads();

  // pass 3: bits [8:0] — dual 512-bin histograms, single scan
  for (int i = tid; i < 512; i += 256) { histH[i] = 0; histL[i] = 0; }
  __syncthreads();
  for (int i = tid; i < M_; i += 256) {
    unsigned kk = samp[i];
    unsigned pp = kk >> 9;
    if (pp == pfxh) atomicAdd(&histH[kk & 0x1FF], 1u);
    if (pp == pfxl) atomicAdd(&histL[kk & 0x1FF], 1u);
  }
  __syncthreads();
  rank_bin<512>(histH, r2h, sb, tid);
  unsigned khi = (pfxh << 9) | sb[0];
  __syncthreads();
  rank_bin<512>(histL, r2l, sb, tid);
  unsigned klo = (pfxl << 9) | sb[0];

  if (tid == 0) {
    ctrl->brackets[2 * pair] = khi;
    ctrl->brackets[2 * pair + 1] = klo;
  }
  if (tid < CCP) ctrl->cand_cnt[pair * CCP + tid] = 0u;
}

// ---------------------------------------------------------------------------
// K2: main pass. grid (864, B); 4 voxels/thread via float4. ALL 28 loads
// issued up front; xt collapsed to one-hot bitmasks immediately (frees 56
// VGPRs) so the full load set stays in flight. launch_bounds(256,2) raises
// the VGPR cap so the compiler doesn't re-serialize the loads.
// ---------------------------------------------------------------------------
__global__ __launch_bounds__(256, 2) void k2_main(const float* __restrict__ pred,
                                                  const float* __restrict__ targ,
                                                  Ctrl* __restrict__ ctrl,
                                                  double* __restrict__ part,
                                                  unsigned* __restrict__ cand_key,
                                                  unsigned* __restrict__ cand_idx,
                                                  unsigned cap) {
  int b = blockIdx.y;
  int tid = threadIdx.x;
  int lane = tid & 63;
  int wv = tid >> 6;
  __shared__ unsigned s_cnt[C_], s_base[C_], s_khi[C_], s_klo[C_];
  __shared__ unsigned s_key[C_][CAPB];
  __shared__ unsigned s_idx[C_][CAPB];
  __shared__ float s_part[4][PS];

  int pr0 = b * C_;
  const size_t gbase = (size_t)b * C_ * N_;
  const int n0 = blockIdx.x * 1024 + tid * 4;

  // issue all 28 16B loads up front (full MLP)
  float4 xp[C_], xt[C_];
#pragma unroll
  for (int c = 0; c < C_; ++c) {
    xp[c] = *reinterpret_cast<const float4*>(pred + gbase + (size_t)c * N_ + n0);
    xt[c] = *reinterpret_cast<const float4*>(targ + gbase + (size_t)c * N_ + n0);
  }

  if (tid < C_) {
    s_khi[tid] = ctrl->brackets[2 * (pr0 + tid)];
    s_klo[tid] = ctrl->brackets[2 * (pr0 + tid) + 1];
    s_cnt[tid] = 0u;
  }

  // collapse one-hot target to 4 bitmasks; xt registers die here
  unsigned tb[4];
  tb[0] = tb[1] = tb[2] = tb[3] = 0u;
#pragma unroll
  for (int c = 0; c < C_; ++c) {
    if (xt[c].x > 0.5f) tb[0] |= 1u << c;
    if (xt[c].y > 0.5f) tb[1] |= 1u << c;
    if (xt[c].z > 0.5f) tb[2] |= 1u << c;
    if (xt[c].w > 0.5f) tb[3] |= 1u << c;
  }
  __syncthreads();

  float4 mx = xp[0];
#pragma unroll
  for (int c = 1; c < C_; ++c) {
    mx.x = fmaxf(mx.x, xp[c].x); mx.y = fmaxf(mx.y, xp[c].y);
    mx.z = fmaxf(mx.z, xp[c].z); mx.w = fmaxf(mx.w, xp[c].w);
  }
  float4 sum; sum.x = 0.f; sum.y = 0.f; sum.z = 0.f; sum.w = 0.f;
#pragma unroll
  for (int c = 0; c < C_; ++c) {
    xp[c].x = __expf(xp[c].x - mx.x); sum.x += xp[c].x;
    xp[c].y = __expf(xp[c].y - mx.y); sum.y += xp[c].y;
    xp[c].z = __expf(xp[c].z - mx.z); sum.z += xp[c].z;
    xp[c].w = __expf(xp[c].w - mx.w); sum.w += xp[c].w;
  }
  float4 rs;
  rs.x = 1.0f / sum.x; rs.y = 1.0f / sum.y; rs.z = 1.0f / sum.z; rs.w = 1.0f / sum.w;

  float a_p2[C_], a_p2t[C_];
  unsigned a_pk[C_];   // packed per-thread counts: cnt<<20 | tsel<<10 | tall (each <=4)
#pragma unroll
  for (int c = 0; c < C_; ++c) { a_p2[c] = 0.f; a_p2t[c] = 0.f; a_pk[c] = 0u; }

#pragma unroll
  for (int c = 0; c < C_; ++c) {
    unsigned khi = s_khi[c], klo = s_klo[c];
#pragma unroll
    for (int h = 0; h < 4; ++h) {
      float p = COMP(xp[c], h) * COMP(rs, h);
      unsigned tbit = (tb[h] >> c) & 1u;
      float err = tbit ? (1.0f - p) : p;   // == fabsf(p - t) exactly (t one-hot)
      unsigned eb = __float_as_uint(err);
      bool above = eb > khi;
      bool iscand = (eb > klo) && !above;
      if (above) {
        float pp = p * p;
        a_p2[c] += pp;
        if (tbit) a_p2t[c] += pp;
      }
      a_pk[c] += (above ? (1u << 20) : 0u) + ((above && tbit) ? (1u << 10) : 0u) + tbit;
      if (iscand) {
        unsigned pos = atomicAdd(&s_cnt[c], 1u);
        unsigned key = (eb << 1) | tbit;
        if (pos < CAPB) {
          s_key[c][pos] = key;
          s_idx[c][pos] = (unsigned)(n0 + h);
        } else {   // rare overflow: direct global (padded counter), still correct
          unsigned off = atomicAdd(&ctrl->cand_cnt[(pr0 + c) * CCP], 1u);
          if (off < cap) {
            size_t cb = (size_t)(pr0 + c) * cap + off;
            cand_key[cb] = key;
            cand_idx[cb] = (unsigned)(n0 + h);
          }
        }
      }
    }
  }

  // block reduction: 3 chains per class (p2, p2t, packed counts)
#pragma unroll
  for (int c = 0; c < C_; ++c) {
    float v0 = a_p2[c], v1 = a_p2t[c];
    unsigned u2 = a_pk[c];
    for (int o = 32; o > 0; o >>= 1) {
      v0 += __shfl_down(v0, o);
      v1 += __shfl_down(v1, o);
      u2 += (unsigned)__shfl_down((int)u2, o);   // wave-sum fields <=256, no carry
    }
    if (lane == 0) {
      s_part[wv][c * 5 + 0] = v0;
      s_part[wv][c * 5 + 1] = v1;
      s_part[wv][c * 5 + 2] = (float)((u2 >> 10) & 0x3FF);  // tsel
      s_part[wv][c * 5 + 3] = (float)(u2 >> 20);            // cntA
      s_part[wv][c * 5 + 4] = (float)(u2 & 0x3FF);          // tall
    }
  }
  __syncthreads();

  if (tid < C_) {   // one padded global atomic per class per block
    unsigned cnt = s_cnt[tid]; if (cnt > CAPB) cnt = CAPB;
    s_base[tid] = atomicAdd(&ctrl->cand_cnt[(pr0 + tid) * CCP], cnt);
  }
  if (tid < PS) {   // per-block partial sums, no atomics
    double v = (double)s_part[0][tid] + (double)s_part[1][tid] +
               (double)s_part[2][tid] + (double)s_part[3][tid];
    part[(size_t)(b * G2 + blockIdx.x) * PS + tid] = v;
  }
  __syncthreads();

  for (int c = 0; c < C_; ++c) {   // coalesced candidate flush
    unsigned cnt = s_cnt[c]; if (cnt > CAPB) cnt = CAPB;
    unsigned bas = s_base[c];
    for (unsigned i = tid; i < cnt; i += 256) {
      unsigned off = bas + i;
      if (off < cap) {
        size_t cb = (size_t)(pr0 + c) * cap + off;
        cand_key[cb] = s_key[c][i];
        cand_idx[cb] = s_idx[c][i];
      }
    }
  }
}

// ---------------------------------------------------------------------------
// K3: reduce partials + exact selection among candidates. Keys staged in LDS
// (112 KB) -> one global read + 3 LDS histogram passes + LDS accumulate.
// ---------------------------------------------------------------------------
__global__ __launch_bounds__(256) void k3_finish(Ctrl* __restrict__ ctrl,
                                                 const double* __restrict__ part,
                                                 const unsigned* __restrict__ cand_key,
                                                 const unsigned* __restrict__ cand_idx,
                                                 unsigned cap) {
  __shared__ unsigned s_keys[KLDS];    // 112 KB
  __shared__ unsigned hist[2048];
  __shared__ unsigned sb[2];
  __shared__ double s_red5[4][5];
  __shared__ double s_sum[5];
  __shared__ unsigned s_ties[TIECAP];
  __shared__ unsigned s_tiecnt;
  __shared__ float redf[4][3];
  int pair = blockIdx.x;
  int b = pair / C_, c = pair % C_;
  int tid = threadIdx.x;
  int lane = tid & 63, wv = tid >> 6;

  // 1. reduce K2 partial sums for this pair
  double acc0 = 0, acc1 = 0, acc2 = 0, acc3 = 0, acc4 = 0;
  for (int g = tid; g < G2; g += 256) {
    const double* pp = part + (size_t)(b * G2 + g) * PS + c * 5;
    acc0 += pp[0]; acc1 += pp[1]; acc2 += pp[2]; acc3 += pp[3]; acc4 += pp[4];
  }
  for (int o = 32; o > 0; o >>= 1) {
    acc0 += __shfl_down(acc0, o); acc1 += __shfl_down(acc1, o);
    acc2 += __shfl_down(acc2, o); acc3 += __shfl_down(acc3, o);
    acc4 += __shfl_down(acc4, o);
  }
  if (lane == 0) {
    s_red5[wv][0] = acc0; s_red5[wv][1] = acc1; s_red5[wv][2] = acc2;
    s_red5[wv][3] = acc3; s_red5[wv][4] = acc4;
  }
  __syncthreads();
  if (tid == 0) {
    for (int q = 0; q < 5; ++q)
      s_sum[q] = s_red5[0][q] + s_red5[1][q] + s_red5[2][q] + s_red5[3][q];
    s_tiecnt = 0;
  }
  __syncthreads();
  double d_p2 = s_sum[0], d_p2t = s_sum[1], d_t = s_sum[2];
  double d_cnt = s_sum[3], d_tall = s_sum[4];

  unsigned nc = ctrl->cand_cnt[pair * CCP];
  if (nc > cap) nc = cap;
  int r = K_ - (int)(d_cnt + 0.5);
  if (r > (int)nc) r = (int)nc;   // fallback (bracket failure); never expected

  double add_p2 = 0, add_p2t = 0, add_t = 0;
  if (r > 0) {
    const unsigned* gkey = cand_key + (size_t)pair * cap;
    const unsigned* gidx = cand_idx + (size_t)pair * cap;
    bool in_lds = (nc <= KLDS);
    if (in_lds)
      for (int i = tid; i < (int)nc; i += 256) s_keys[i] = gkey[i];
    __syncthreads();
    const unsigned* key = in_lds ? (const unsigned*)s_keys : gkey;

    // level 1: err bits [30:20] == key>>21
    for (int i = tid; i < 2048; i += 256) hist[i] = 0;
    __syncthreads();
    for (int i = tid; i < (int)nc; i += 256) atomicAdd(&hist[key[i] >> 21], 1u);
    __syncthreads();
    rank_bin<2048>(hist, r, sb, tid);
    unsigned b1 = sb[0]; int r1 = (int)sb[1];
    __syncthreads();
    // level 2: err bits [19:9]
    for (int i = tid; i < 2048; i += 256) hist[i] = 0;
    __syncthreads();
    for (int i = tid; i < (int)nc; i += 256) {
      unsigned kk = key[i];
      if ((kk >> 21) == b1) atomicAdd(&hist[(kk >> 10) & 0x7FF], 1u);
    }
    __syncthreads();
    rank_bin<2048>(hist, r1, sb, tid);
    unsigned b2 = sb[0]; int r2 = (int)sb[1];
    unsigned pfx22 = (b1 << 11) | b2;
    __syncthreads();
    // level 3: err bits [8:0]
    for (int i = tid; i < 512; i += 256) hist[i] = 0;
    __syncthreads();
    for (int i = tid; i < (int)nc; i += 256) {
      unsigned kk = key[i];
      if ((kk >> 10) == pfx22) atomicAdd(&hist[(kk >> 1) & 0x1FF], 1u);
    }
    __syncthreads();
    rank_bin<512>(hist, r2, sb, tid);
    unsigned tau = (pfx22 << 9) | sb[0];
    int need = (int)sb[1];

    // accumulate strictly-above + collect ties at tau
    float f_p2 = 0.f, f_p2t = 0.f, f_t = 0.f;
    for (int i = tid; i < (int)nc; i += 256) {
      unsigned kk = key[i];
      unsigned eb = kk >> 1;
      if (eb > tau) {
        float err = __uint_as_float(eb);
        float t = (float)(kk & 1u);
        float p = (kk & 1u) ? (1.f - err) : err;
        float pp = p * p;
        f_p2 += pp; f_p2t += pp * t; f_t += t;
      } else if (eb == tau) {
        unsigned pos = atomicAdd(&s_tiecnt, 1u);
        if (pos < TIECAP) s_ties[pos] = (gidx[i] << 1) | (kk & 1u);  // idx < 2^20
      }
    }
    for (int o = 32; o > 0; o >>= 1) {
      f_p2 += __shfl_down(f_p2, o); f_p2t += __shfl_down(f_p2t, o);
      f_t += __shfl_down(f_t, o);
    }
    if (lane == 0) { redf[wv][0] = f_p2; redf[wv][1] = f_p2t; redf[wv][2] = f_t; }
    __syncthreads();

    if (tid == 0) {
      add_p2  = (double)redf[0][0] + redf[1][0] + redf[2][0] + redf[3][0];
      add_p2t = (double)redf[0][1] + redf[1][1] + redf[2][1] + redf[3][1];
      add_t   = (double)redf[0][2] + redf[1][2] + redf[2][2] + redf[3][2];
      // ties at exactly tau: jax takes lowest indices first
      unsigned tc = s_tiecnt; if (tc > TIECAP) tc = TIECAP;
      int take = need; if (take > (int)tc) take = (int)tc;
      float errf = __uint_as_float(tau);
      for (int s = 0; s < take; ++s) {
        unsigned best = 0xFFFFFFFFu; int bi = -1;
        for (int j = 0; j < (int)tc; ++j)
          if (s_ties[j] < best) { best = s_ties[j]; bi = j; }
        if (bi < 0) break;
        s_ties[bi] = 0xFFFFFFFFu;
        float t = (float)(best & 1u);
        float p = (best & 1u) ? (1.f - errf) : errf;
        add_p2 += (double)(p * p); add_p2t += (double)(p * p) * t; add_t += (double)t;
      }
    }
  }

  if (tid == 0) {
    ctrl->sum_p2[pair]   = d_p2 + add_p2;
    ctrl->sum_p2t[pair]  = d_p2t + add_p2t;
    ctrl->sum_t[pair]    = d_t + add_t;
    ctrl->sum_tall[pair] = d_tall;
    ctrl->cntA[pair]     = d_cnt;
  }
}

// ---------------------------------------------------------------------------
// K4: final scalar
// ---------------------------------------------------------------------------
__global__ void k4_final(const Ctrl* __restrict__ ctrl, float* __restrict__ out) {
  if (threadIdx.x == 0 && blockIdx.x == 0) {
    double total = 0.0, nb = 0.0;
    for (int b = 0; b < B_; ++b) {
      double sl = 0.0, nv = 0.0;
      for (int c = 0; c < C_; ++c) {
        int pr = b * C_ + c;
        if (ctrl->sum_tall[pr] > 0.0) {
          double inter = ctrl->sum_p2t[pr];
          double uni = ctrl->sum_p2[pr] + ctrl->sum_t[pr];
          double dice = (2.0 * inter + EPS_) / (uni + EPS_);
          sl += 1.0 - dice;
          nv += 1.0;
        }
      }
      if (nv > 0.0) { total += sl / nv; nb += 1.0; }
    }
    out[0] = (float)(nb > 0.0 ? total / nb : 0.0);
  }
}

// ---------------------------------------------------------------------------
extern "C" void kernel_launch(void* const* d_in, const int* in_sizes, int n_in,
                              void* d_out, int out_size, void* d_ws, size_t ws_size,
                              hipStream_t stream) {
  const float* pred = (const float*)d_in[0];
  const float* targ = (const float*)d_in[1];
  Ctrl* ctrl = (Ctrl*)d_ws;
  double* part = (double*)((char*)d_ws + 4096);
  size_t part_bytes = (size_t)(B_ * G2) * PS * sizeof(double);   // 968 KB
  size_t samp_off = (4096 + part_bytes + 255) & ~(size_t)255;
  unsigned* sampkeys = (unsigned*)((char*)d_ws + samp_off);
  size_t cand_off = (samp_off + (size_t)NP * M_ * 4 + 255) & ~(size_t)255;

  unsigned cap = CAPMAX;
  if (ws_size > cand_off + 1024) {
    size_t avail = (ws_size - cand_off) / (8 * NP);   // 2 uints per candidate
    if (avail < (size_t)cap) cap = (unsigned)avail;
  } else {
    cap = 1;
  }
  unsigned* cand_key = (unsigned*)((char*)d_ws + cand_off);
  unsigned* cand_idx = cand_key + (size_t)NP * cap;
  float* out = (float*)d_out;

  k1a_sample<<<dim3(MBLK, B_), dim3(256), 0, stream>>>(pred, targ, sampkeys);
  k1b_bracket<<<dim3(NP), dim3(256), 0, stream>>>(sampkeys, ctrl);
  k2_main<<<dim3(G2, B_), dim3(256), 0, stream>>>(pred, targ, ctrl, part, cand_key, cand_idx, cap);
  k3_finish<<<dim3(NP), dim3(256), 0, stream>>>(ctrl, part, cand_key, cand_idx, cap);
  k4_final<<<dim3(1), dim3(1), 0, stream>>>(ctrl, out);
}